// Round 8
// baseline (26.510 us; speedup 1.0000x reference)
//
#include <hip/hip_runtime.h>
#include <hip/hip_bf16.h>
#include <math.h>

// Problem constants (from reference setup_inputs)
#define BATCH   512          // bs * n_vars = 64 * 8
#define KP      3            // k_positive
#define KN      16           // k_negative
#define KTOT    (KP + KN)    // 19
#define PD      8192         // P * D = 64 * 128
#define INV_T   50.0f        // 1 / temperature (0.02)

#define SPLIT   8            // blocks per sample == #XCDs (part == XCD id)
#define CHUNK   (PD / SPLIT) // 1024 floats per block (4 KB slice per row)
#define THREADS 256          // 256 threads * 4 floats = 1024 (dense 1 f32x4/thread)

typedef float f32x4 __attribute__((ext_vector_type(4)));

__global__ __launch_bounds__(THREADS)
void agg_rebuild_kernel(const float* __restrict__ sim,
                        const float* __restrict__ p_enc,
                        const int*   __restrict__ neg_idx,
                        float*       __restrict__ out) {
    const int b    = blockIdx.x >> 3;        // sample index (block-uniform)
    const int part = blockIdx.x & (SPLIT-1); // d-slice == XCD id (round-robin)
    const int tid  = threadIdx.x;

    // --- softmax over 19 temperature-scaled scores, computed redundantly by
    // every lane from block-uniform addresses: compiler scalarizes these to
    // s_load and keeps everything in SGPRs. No LDS, no barriers.
    float w[KTOT];
    float m = -INFINITY;
    #pragma unroll
    for (int k = 0; k < KTOT; ++k) {
        w[k] = sim[b * KTOT + k] * INV_T;
        m = fmaxf(m, w[k]);
    }
    float s = 0.0f;
    #pragma unroll
    for (int k = 0; k < KTOT; ++k) {
        w[k] = __expf(w[k] - m);
        s += w[k];
    }
    const float inv = 1.0f / s;

    // --- row base pointers, all block-uniform -> SGPR pairs.
    const float* rowp[KTOT];
    #pragma unroll
    for (int k = 0; k < KP; ++k)
        rowp[k] = p_enc + (size_t)(BATCH + b * KP + k) * PD;
    #pragma unroll
    for (int k = 0; k < KN; ++k)
        rowp[KP + k] = p_enc + (size_t)neg_idx[b * KN + k] * PD;

    // --- weighted sum of 19 rows, one dense f32x4 per thread (fully coalesced:
    // each wave load instruction covers one contiguous 1 KB segment).
    const int d = part * CHUNK + tid * 4;
    f32x4 acc = {0.f, 0.f, 0.f, 0.f};

    // positives: single-use stream -> nontemporal (evict-first) LOADS ONLY,
    // so they stop evicting the L2-resident negative slice. Stores stay normal
    // (R4 showed nt stores cost ~4 us).
    #pragma unroll
    for (int k = 0; k < KP; ++k) {
        const f32x4 x = __builtin_nontemporal_load(
            reinterpret_cast<const f32x4*>(rowp[k] + d));
        acc += (w[k] * inv) * x;
    }
    // negatives: reused ~16x, 2 MB/XCD working set -> want L2-resident
    #pragma unroll
    for (int k = KP; k < KTOT; ++k) {
        const f32x4 x = *reinterpret_cast<const f32x4*>(rowp[k] + d);
        acc += (w[k] * inv) * x;
    }

    *reinterpret_cast<f32x4*>(out + (size_t)b * PD + d) = acc;
}

extern "C" void kernel_launch(void* const* d_in, const int* in_sizes, int n_in,
                              void* d_out, int out_size, void* d_ws, size_t ws_size,
                              hipStream_t stream) {
    const float* sim     = (const float*)d_in[0];   // [B, 19]
    const float* p_enc   = (const float*)d_in[1];   // [B*(1+KP), P, D]
    const int*   neg_idx = (const int*)d_in[2];     // [B, KN]
    float*       out     = (float*)d_out;           // [B, P, D]

    dim3 grid(BATCH * SPLIT);
    dim3 block(THREADS);
    agg_rebuild_kernel<<<grid, block, 0, stream>>>(sim, p_enc, neg_idx, out);
}

// Round 9
// 26.277 us; speedup vs baseline: 1.0089x; 1.0089x over previous
//
#include <hip/hip_runtime.h>
#include <hip/hip_bf16.h>
#include <math.h>

// Problem constants (from reference setup_inputs)
#define BATCH   512          // bs * n_vars = 64 * 8
#define KP      3            // k_positive
#define KN      16           // k_negative
#define KTOT    (KP + KN)    // 19
#define PD      8192         // P * D = 64 * 128
#define INV_T   50.0f        // 1 / temperature (0.02)

#define SPLIT   8            // blocks per sample == #XCDs (part == XCD id)
#define CHUNK   (PD / SPLIT) // 1024 floats per block (4 KB slice per row)
#define THREADS 256          // 256 threads * 4 floats = 1024 (dense 1 f32x4/thread)

typedef float          f32x4 __attribute__((ext_vector_type(4)));
typedef unsigned short u16x4 __attribute__((ext_vector_type(4)));
typedef unsigned short u16x8 __attribute__((ext_vector_type(8)));

static __device__ __forceinline__ float bf16_bits_to_f32(unsigned short u) {
    union { unsigned int i; float f; } c;
    c.i = (unsigned int)u << 16;
    return c.f;
}

// --- kernel 1: convert negatives panel (rows 0..511 of p_enc) to bf16 in d_ws.
// 4,194,304 elems / 8 per thread = 524288 threads = 2048 blocks x 256.
__global__ __launch_bounds__(256)
void cvt_panel_kernel(const float* __restrict__ src,
                      unsigned short* __restrict__ dst) {
    const int i = (blockIdx.x * 256 + threadIdx.x) * 8;
    const f32x4 a = *reinterpret_cast<const f32x4*>(src + i);
    const f32x4 b = *reinterpret_cast<const f32x4*>(src + i + 4);
    u16x8 o;
    #pragma unroll
    for (int j = 0; j < 4; ++j) {
        __hip_bfloat16 ha = __float2bfloat16(a[j]);   // RNE
        __hip_bfloat16 hb = __float2bfloat16(b[j]);
        o[j]     = *reinterpret_cast<unsigned short*>(&ha);
        o[j + 4] = *reinterpret_cast<unsigned short*>(&hb);
    }
    *reinterpret_cast<u16x8*>(dst + i) = o;
}

// --- kernel 2 (bf16-negatives variant of the R5 structure)
__global__ __launch_bounds__(THREADS)
void agg_rebuild_bf16_kernel(const float* __restrict__ sim,
                             const float* __restrict__ p_enc,
                             const int*   __restrict__ neg_idx,
                             const unsigned short* __restrict__ panel,
                             float*       __restrict__ out) {
    const int b    = blockIdx.x >> 3;        // sample index (block-uniform)
    const int part = blockIdx.x & (SPLIT-1); // d-slice == XCD id (round-robin)
    const int tid  = threadIdx.x;

    // softmax over 19 temperature-scaled scores, redundantly in all lanes from
    // block-uniform addresses (scalarizes to s_load; no LDS, no barriers).
    float w[KTOT];
    float m = -INFINITY;
    #pragma unroll
    for (int k = 0; k < KTOT; ++k) {
        w[k] = sim[b * KTOT + k] * INV_T;
        m = fmaxf(m, w[k]);
    }
    float s = 0.0f;
    #pragma unroll
    for (int k = 0; k < KTOT; ++k) {
        w[k] = __expf(w[k] - m);
        s += w[k];
    }
    const float inv = 1.0f / s;

    const int d = part * CHUNK + tid * 4;
    f32x4 acc = {0.f, 0.f, 0.f, 0.f};

    // positives: f32, streamed once, dense 1 KB/wave-instruction
    #pragma unroll
    for (int k = 0; k < KP; ++k) {
        const f32x4 x = *reinterpret_cast<const f32x4*>(
            p_enc + (size_t)(BATCH + b * KP + k) * PD + d);
        acc += (w[k] * inv) * x;
    }
    // negatives: bf16 panel gather (8 B/lane), halves the cache-serve bytes
    #pragma unroll
    for (int k = 0; k < KN; ++k) {
        const int row = neg_idx[b * KN + k];
        const u16x4 v = *reinterpret_cast<const u16x4*>(
            panel + (size_t)row * PD + d);
        const float wk = w[KP + k] * inv;
        f32x4 x = {bf16_bits_to_f32(v[0]), bf16_bits_to_f32(v[1]),
                   bf16_bits_to_f32(v[2]), bf16_bits_to_f32(v[3])};
        acc += wk * x;
    }

    *reinterpret_cast<f32x4*>(out + (size_t)b * PD + d) = acc;
}

// --- fallback: pure-f32 R5 kernel (used only if ws_size is too small)
__global__ __launch_bounds__(THREADS)
void agg_rebuild_f32_kernel(const float* __restrict__ sim,
                            const float* __restrict__ p_enc,
                            const int*   __restrict__ neg_idx,
                            float*       __restrict__ out) {
    const int b    = blockIdx.x >> 3;
    const int part = blockIdx.x & (SPLIT-1);
    const int tid  = threadIdx.x;

    float w[KTOT];
    float m = -INFINITY;
    #pragma unroll
    for (int k = 0; k < KTOT; ++k) {
        w[k] = sim[b * KTOT + k] * INV_T;
        m = fmaxf(m, w[k]);
    }
    float s = 0.0f;
    #pragma unroll
    for (int k = 0; k < KTOT; ++k) {
        w[k] = __expf(w[k] - m);
        s += w[k];
    }
    const float inv = 1.0f / s;

    const float* rowp[KTOT];
    #pragma unroll
    for (int k = 0; k < KP; ++k)
        rowp[k] = p_enc + (size_t)(BATCH + b * KP + k) * PD;
    #pragma unroll
    for (int k = 0; k < KN; ++k)
        rowp[KP + k] = p_enc + (size_t)neg_idx[b * KN + k] * PD;

    const int d = part * CHUNK + tid * 4;
    f32x4 acc = {0.f, 0.f, 0.f, 0.f};
    #pragma unroll
    for (int k = 0; k < KTOT; ++k) {
        const f32x4 x = *reinterpret_cast<const f32x4*>(rowp[k] + d);
        acc += (w[k] * inv) * x;
    }
    *reinterpret_cast<f32x4*>(out + (size_t)b * PD + d) = acc;
}

extern "C" void kernel_launch(void* const* d_in, const int* in_sizes, int n_in,
                              void* d_out, int out_size, void* d_ws, size_t ws_size,
                              hipStream_t stream) {
    const float* sim     = (const float*)d_in[0];   // [B, 19]
    const float* p_enc   = (const float*)d_in[1];   // [B*(1+KP), P, D]
    const int*   neg_idx = (const int*)d_in[2];     // [B, KN]
    float*       out     = (float*)d_out;           // [B, P, D]

    const size_t panel_bytes = (size_t)BATCH * PD * sizeof(unsigned short);
    if (ws_size >= panel_bytes) {
        unsigned short* panel = (unsigned short*)d_ws;
        cvt_panel_kernel<<<dim3(BATCH * PD / (8 * 256)), dim3(256), 0, stream>>>(
            p_enc, panel);
        agg_rebuild_bf16_kernel<<<dim3(BATCH * SPLIT), dim3(THREADS), 0, stream>>>(
            sim, p_enc, neg_idx, panel, out);
    } else {
        agg_rebuild_f32_kernel<<<dim3(BATCH * SPLIT), dim3(THREADS), 0, stream>>>(
            sim, p_enc, neg_idx, out);
    }
}

// Round 10
// 20.547 us; speedup vs baseline: 1.2902x; 1.2789x over previous
//
#include <hip/hip_runtime.h>
#include <hip/hip_bf16.h>
#include <math.h>

// Problem constants (from reference setup_inputs)
#define BATCH   512          // bs * n_vars = 64 * 8
#define KP      3            // k_positive
#define KN      16           // k_negative
#define KTOT    (KP + KN)    // 19
#define PD      8192         // P * D = 64 * 128
#define INV_T   50.0f        // 1 / temperature (0.02)

#define SPLIT   8            // blocks per sample == #XCDs (part == XCD id)
#define CHUNK   (PD / SPLIT) // 1024 floats per block (4 KB slice per row)
#define THREADS 256          // 256 threads * 4 floats = 1024 (dense 1 f32x4/thread)

typedef float f32x4 __attribute__((ext_vector_type(4)));

__global__ __launch_bounds__(THREADS)
void agg_rebuild_kernel(const float* __restrict__ sim,
                        const float* __restrict__ p_enc,
                        const int*   __restrict__ neg_idx,
                        float*       __restrict__ out) {
    const int b    = blockIdx.x >> 3;        // sample index (block-uniform)
    const int part = blockIdx.x & (SPLIT-1); // d-slice == XCD id (round-robin)
    const int tid  = threadIdx.x;

    // --- softmax over 19 temperature-scaled scores, computed redundantly by
    // every lane from block-uniform addresses: compiler scalarizes these to
    // s_load and keeps everything in SGPRs. No LDS, no barriers.
    float w[KTOT];
    float m = -INFINITY;
    #pragma unroll
    for (int k = 0; k < KTOT; ++k) {
        w[k] = sim[b * KTOT + k] * INV_T;
        m = fmaxf(m, w[k]);
    }
    float s = 0.0f;
    #pragma unroll
    for (int k = 0; k < KTOT; ++k) {
        w[k] = __expf(w[k] - m);
        s += w[k];
    }
    const float inv = 1.0f / s;

    // --- row base pointers, all block-uniform -> SGPR pairs.
    const float* rowp[KTOT];
    #pragma unroll
    for (int k = 0; k < KP; ++k)
        rowp[k] = p_enc + (size_t)(BATCH + b * KP + k) * PD;
    #pragma unroll
    for (int k = 0; k < KN; ++k)
        rowp[KP + k] = p_enc + (size_t)neg_idx[b * KN + k] * PD;

    // --- weighted sum of 19 rows, one dense f32x4 per thread (fully coalesced:
    // each wave load instruction covers one contiguous 1 KB segment).
    const int d = part * CHUNK + tid * 4;
    f32x4 acc = {0.f, 0.f, 0.f, 0.f};
    #pragma unroll
    for (int k = 0; k < KTOT; ++k) {
        const f32x4 x = *reinterpret_cast<const f32x4*>(rowp[k] + d);
        acc += (w[k] * inv) * x;
    }

    *reinterpret_cast<f32x4*>(out + (size_t)b * PD + d) = acc;
}

extern "C" void kernel_launch(void* const* d_in, const int* in_sizes, int n_in,
                              void* d_out, int out_size, void* d_ws, size_t ws_size,
                              hipStream_t stream) {
    const float* sim     = (const float*)d_in[0];   // [B, 19]
    const float* p_enc   = (const float*)d_in[1];   // [B*(1+KP), P, D]
    const int*   neg_idx = (const int*)d_in[2];     // [B, KN]
    float*       out     = (float*)d_out;           // [B, P, D]

    dim3 grid(BATCH * SPLIT);
    dim3 block(THREADS);
    agg_rebuild_kernel<<<grid, block, 0, stream>>>(sim, p_enc, neg_idx, out);
}